// Round 11
// baseline (86.727 us; speedup 1.0000x reference)
//
#include <hip/hip_runtime.h>
#include <math.h>

// Tropical max/min-plus pseudo-matmul.
// out[b,u] = max_f(x[b,f] + w[f,u]) for u<128, min_f otherwise.
//
// R10 diagnostic (idempotent double-pass): k-loop = 10.7us/pass, fixed
// overhead ~12us. Loop 10.7 = VALU 5.5 + LDS 5.1 SUMMING: reads and uses in
// the same iteration expose full LDS service time (lgkmcnt wait right after
// issue). R11: within-wave software pipeline for x — A/B register buffers
// (8 x b128), unroll-1 over quad-PAIRS, so ~416 cyc of compute separates
// read-issue from first use. w demand-loaded per k-pair, sign folded in
// place. Regs: acc 32 + xA 32 + xB 32 + w 8 + addr ~8 = ~112 < 128 cap.
// Structure otherwise identical to R9 (BR=8, U=4, NW=16, KW=32, 1 blk/CU).

#define FEAT  512
#define UNITS 256
#define BR    8     // rows per block
#define KW    32    // k per wave
#define NW    16    // waves per block
#define NQ    (KW / 4)   // 8 quads per wave

__device__ __forceinline__ float max3(float a, float b, float c) {
    return fmaxf(fmaxf(a, b), c);   // v_max3_f32
}

// issue 8 broadcast ds_read_b128 for quad q (rows 0..7, k = kb+q*4 .. +3)
__device__ __forceinline__ void load_quad(const float* __restrict__ lds, int kb, int q,
                                          float4* __restrict__ xb) {
    #pragma unroll
    for (int r = 0; r < BR; ++r)
        xb[r] = *(const float4*)&lds[r * FEAT + kb + q * 4];
}

// compute one quad from register buffer xb; w demand-loaded per k-pair
__device__ __forceinline__ void compute_quad(const float* __restrict__ wp, int q,
                                             float sgn, const float4* __restrict__ xb,
                                             float4* __restrict__ acc) {
    #pragma unroll
    for (int kp = 0; kp < 2; ++kp) {
        const int k0 = q * 4 + kp * 2;
        float4 wa = *(const float4*)(wp + (size_t)k0 * UNITS);
        float4 wb = *(const float4*)(wp + (size_t)(k0 + 1) * UNITS);
        // fold per-lane sign into w in place (8 muls per k-pair)
        wa.x *= sgn; wa.y *= sgn; wa.z *= sgn; wa.w *= sgn;
        wb.x *= sgn; wb.y *= sgn; wb.z *= sgn; wb.w *= sgn;
        #pragma unroll
        for (int r = 0; r < BR; ++r) {
            const float a0 = (kp == 0) ? xb[r].x : xb[r].z;
            const float a1 = (kp == 0) ? xb[r].y : xb[r].w;
            float4 A = acc[r];
            A.x = max3(A.x, fmaf(a0, sgn, wa.x), fmaf(a1, sgn, wb.x));
            A.y = max3(A.y, fmaf(a0, sgn, wa.y), fmaf(a1, sgn, wb.y));
            A.z = max3(A.z, fmaf(a0, sgn, wa.z), fmaf(a1, sgn, wb.z));
            A.w = max3(A.w, fmaf(a0, sgn, wa.w), fmaf(a1, sgn, wb.w));
            acc[r] = A;
        }
    }
}

__global__ __launch_bounds__(1024, 1) void tropical_kernel(const float* __restrict__ x,
                                                           const float* __restrict__ w,
                                                           float* __restrict__ out) {
    __shared__ float lds[NW * BR * UNITS];   // 128 KB; x tile uses first 16 KB
    const int tid  = threadIdx.x;
    const int lane = tid & 63;
    const int wv   = __builtin_amdgcn_readfirstlane(tid >> 6);  // 0..15
    const int u0   = lane * 4;                                  // 0..252
    const float sgn = (lane < 32) ? 1.0f : -1.0f;               // min half negated
    const int row0 = blockIdx.x * BR;
    const int kb   = wv * KW;

    // ---- stage x tile (8 rows x 512 = 16 KB), one float4 per thread ----
    {
        const float4* src = (const float4*)(x + (size_t)row0 * FEAT);
        ((float4*)lds)[tid] = src[tid];
    }

    const float* wp = w + (size_t)kb * UNITS + u0;   // dwordx4, 1KB/wave-instr

    float4 acc[BR];
    #pragma unroll
    for (int r = 0; r < BR; ++r)
        acc[r] = make_float4(-__builtin_inff(), -__builtin_inff(),
                             -__builtin_inff(), -__builtin_inff());

    __syncthreads();   // x tile visible

    // ---- software-pipelined main loop: x reads one quad ahead ----
    float4 xA[BR], xB[BR];
    load_quad(lds, kb, 0, xA);

    #pragma unroll 1
    for (int q = 0; q < NQ; q += 2) {
        load_quad(lds, kb, q + 1, xB);       // issue next-quad reads early
        compute_quad(wp, q, sgn, xA, acc);   // ~416 cyc cover the B reads
        if (q + 2 < NQ)
            load_quad(lds, kb, q + 2, xA);
        compute_quad(wp, q + 1, sgn, xB, acc);
    }

    // ---- combine 16 k-partials via LDS (reuses x region; 128 KB) ----
    __syncthreads();   // all waves done reading x tile
    #pragma unroll
    for (int r = 0; r < BR; ++r)
        *(float4*)&lds[((wv * BR + r) * UNITS) + u0] = acc[r];
    __syncthreads();

    // thread -> output pair: r = tid>>7 (0..7), units up0..up0+1
    const int r   = tid >> 7;
    const int up0 = (tid & 127) * 2;
    float2 v = *(const float2*)&lds[(0 * BR + r) * UNITS + up0];
    #pragma unroll
    for (int j = 1; j < NW; ++j) {
        const float2 p = *(const float2*)&lds[(j * BR + r) * UNITS + up0];
        v.x = fmaxf(v.x, p.x);
        v.y = fmaxf(v.y, p.y);
    }
    const float so = (up0 < 128) ? 1.0f : -1.0f;   // undo negation for min half
    *(float2*)&out[(size_t)(row0 + r) * UNITS + up0] = make_float2(v.x * so, v.y * so);
}

extern "C" void kernel_launch(void* const* d_in, const int* in_sizes, int n_in,
                              void* d_out, int out_size, void* d_ws, size_t ws_size,
                              hipStream_t stream) {
    const float* x = (const float*)d_in[0];   // (2048, 512)
    const float* w = (const float*)d_in[1];   // (512, 256)
    float* out = (float*)d_out;               // (2048, 256)

    // 256 blocks x 16 waves = 4096 waves = 4/SIMD, exactly 1 block per CU
    tropical_kernel<<<dim3(2048 / BR), dim3(1024), 0, stream>>>(x, w, out);
}

// Round 12
// 67.520 us; speedup vs baseline: 1.2845x; 1.2845x over previous
//
#include <hip/hip_runtime.h>
#include <math.h>

// Tropical max/min-plus pseudo-matmul.
// out[b,u] = max_f(x[b,f] + w[f,u]) for u<128, min_f otherwise.
//
// R10 measured: R9 loop = 10.7us = VALU 5.5 + LDS 5.1 SUMMING (waits on own
// loads inside the iteration; phase-locked waves don't cover each other).
// R11 regressed by demand-loading w (vmcnt(0) per k-pair) under the 1024-thr
// structural 128-VGPR cap. R12: BOTH operands pipelined one full quad ahead
// (~416 cyc compute covers 250cyc L2 + LDS service). Needs acc32+x64+w32
// ~140 VGPR -> 512-thr blocks (2 waves/SIMD min -> 256 VGPR allowed).
// 256 blocks = 1/CU, BR=8, KW=64, latency hidden by ILP not TLP.
// Sign-fold at USE time (w's vmcnt retired a quad ago). U=4/lane, per-lane
// sign fold (lanes>=32 compute -(x+w) via fma, exact), LDS combine of 8.

#define FEAT  512
#define UNITS 256
#define BR    8          // rows per block
#define KW    64         // k per wave
#define NW    8          // waves per block
#define NQ    (KW / 4)   // 16 quads per wave

__device__ __forceinline__ float max3(float a, float b, float c) {
    return fmaxf(fmaxf(a, b), c);   // v_max3_f32
}

// 8 broadcast ds_read_b128 (rows 0..7, k = kb+q*4..+3); all imm offsets
__device__ __forceinline__ void load_xquad(const float* __restrict__ lds, int kb, int q,
                                           float4* __restrict__ xb) {
    #pragma unroll
    for (int r = 0; r < BR; ++r)
        xb[r] = *(const float4*)&lds[r * FEAT + kb + q * 4];
}

// 4 global dwordx4: w[k][u0..u0+3] for the quad's 4 k values
__device__ __forceinline__ void load_wquad(const float* __restrict__ wp, int q,
                                           float4* __restrict__ wb) {
    #pragma unroll
    for (int k = 0; k < 4; ++k)
        wb[k] = *(const float4*)(wp + (size_t)(q * 4 + k) * UNITS);
}

__device__ __forceinline__ void compute_quad(const float4* __restrict__ xb,
                                             const float4* __restrict__ wq,
                                             float sgn, float4* __restrict__ acc) {
    // fold per-lane sign into w at use time (loads retired >= 1 quad ago)
    const float4 w0 = make_float4(wq[0].x*sgn, wq[0].y*sgn, wq[0].z*sgn, wq[0].w*sgn);
    const float4 w1 = make_float4(wq[1].x*sgn, wq[1].y*sgn, wq[1].z*sgn, wq[1].w*sgn);
    const float4 w2 = make_float4(wq[2].x*sgn, wq[2].y*sgn, wq[2].z*sgn, wq[2].w*sgn);
    const float4 w3 = make_float4(wq[3].x*sgn, wq[3].y*sgn, wq[3].z*sgn, wq[3].w*sgn);
    #pragma unroll
    for (int r = 0; r < BR; ++r) {
        const float4 a = xb[r];
        float4 A = acc[r];
        A.x = max3(A.x, fmaf(a.x, sgn, w0.x), fmaf(a.y, sgn, w1.x));
        A.x = max3(A.x, fmaf(a.z, sgn, w2.x), fmaf(a.w, sgn, w3.x));
        A.y = max3(A.y, fmaf(a.x, sgn, w0.y), fmaf(a.y, sgn, w1.y));
        A.y = max3(A.y, fmaf(a.z, sgn, w2.y), fmaf(a.w, sgn, w3.y));
        A.z = max3(A.z, fmaf(a.x, sgn, w0.z), fmaf(a.y, sgn, w1.z));
        A.z = max3(A.z, fmaf(a.z, sgn, w2.z), fmaf(a.w, sgn, w3.z));
        A.w = max3(A.w, fmaf(a.x, sgn, w0.w), fmaf(a.y, sgn, w1.w));
        A.w = max3(A.w, fmaf(a.z, sgn, w2.w), fmaf(a.w, sgn, w3.w));
        acc[r] = A;
    }
}

__global__ __launch_bounds__(512) void tropical_kernel(const float* __restrict__ x,
                                                       const float* __restrict__ w,
                                                       float* __restrict__ out) {
    __shared__ float lds[NW * BR * UNITS];   // 64 KB; x tile in first 16 KB
    const int tid  = threadIdx.x;
    const int lane = tid & 63;
    const int wv   = __builtin_amdgcn_readfirstlane(tid >> 6);  // 0..7
    const int u0   = lane * 4;                                  // 0..252
    const float sgn = (lane < 32) ? 1.0f : -1.0f;               // min half negated
    const int row0 = blockIdx.x * BR;
    const int kb   = wv * KW;

    // ---- stage x tile (8 rows x 512 = 16 KB), two float4 per thread ----
    {
        const float4* src = (const float4*)(x + (size_t)row0 * FEAT);
        ((float4*)lds)[tid]       = src[tid];
        ((float4*)lds)[tid + 512] = src[tid + 512];
    }

    const float* wp = w + (size_t)kb * UNITS + u0;

    float4 acc[BR];
    #pragma unroll
    for (int r = 0; r < BR; ++r)
        acc[r] = make_float4(-__builtin_inff(), -__builtin_inff(),
                             -__builtin_inff(), -__builtin_inff());

    // prologue w prefetch overlaps the staging barrier
    float4 xA[BR], xB[BR], wA[4], wB[4];
    load_wquad(wp, 0, wA);

    __syncthreads();   // x tile visible
    load_xquad(lds, kb, 0, xA);

    // ---- fully software-pipelined main loop: x AND w one quad ahead ----
    #pragma unroll 1
    for (int q = 0; q < NQ; q += 2) {
        load_wquad(wp, q + 1, wB);
        load_xquad(lds, kb, q + 1, xB);
        compute_quad(xA, wA, sgn, acc);      // covers the B-loads
        if (q + 2 < NQ) {
            load_wquad(wp, q + 2, wA);
            load_xquad(lds, kb, q + 2, xA);
        }
        compute_quad(xB, wB, sgn, acc);      // covers the A-loads
    }

    // ---- combine 8 k-partials via LDS (reuses x region; 64 KB) ----
    __syncthreads();   // all waves done reading x tile
    #pragma unroll
    for (int r = 0; r < BR; ++r)
        *(float4*)&lds[((wv * BR + r) * UNITS) + u0] = acc[r];   // lane-consecutive b128
    __syncthreads();

    // thread -> float4 of output: r = tid>>6 (0..7), units uo..uo+3
    const int r  = tid >> 6;
    const int uo = (tid & 63) * 4;
    float4 v = *(const float4*)&lds[(0 * BR + r) * UNITS + uo];
    #pragma unroll
    for (int j = 1; j < NW; ++j) {
        const float4 p = *(const float4*)&lds[(j * BR + r) * UNITS + uo];
        v.x = fmaxf(v.x, p.x);
        v.y = fmaxf(v.y, p.y);
        v.z = fmaxf(v.z, p.z);
        v.w = fmaxf(v.w, p.w);
    }
    const float so = (uo < 128) ? 1.0f : -1.0f;    // undo negation for min half
    *(float4*)&out[(size_t)(row0 + r) * UNITS + uo] =
        make_float4(v.x * so, v.y * so, v.z * so, v.w * so);
}

extern "C" void kernel_launch(void* const* d_in, const int* in_sizes, int n_in,
                              void* d_out, int out_size, void* d_ws, size_t ws_size,
                              hipStream_t stream) {
    const float* x = (const float*)d_in[0];   // (2048, 512)
    const float* w = (const float*)d_in[1];   // (512, 256)
    float* out = (float*)d_out;               // (2048, 256)

    // 256 blocks x 8 waves = 2048 waves = 2/SIMD, 1 block/CU; ILP-pipelined
    tropical_kernel<<<dim3(2048 / BR), dim3(512), 0, stream>>>(x, w, out);
}